// Round 4
// baseline (429.225 us; speedup 1.0000x reference)
//
#include <hip/hip_runtime.h>
#include <math.h>

#define B_  2
#define S_  2048
#define D_  1024
#define H_  16
#define HD_ 64
#define NT_ (S_/64)          // 32 key tiles
#define SCALE_ 0.125f        // 1/sqrt(64)
#define C2_   (0.125f * 1.44269504088896f)   // scale * log2(e)

typedef __attribute__((ext_vector_type(8))) short bf16x8;
typedef __attribute__((ext_vector_type(4))) float f32x4;
typedef unsigned short u16;

__device__ inline u16 f2bf(float f) {
    union { float f; unsigned u; } c; c.f = f;
    unsigned u = c.u;
    u += 0x7fffu + ((u >> 16) & 1u);       // round-to-nearest-even
    return (u16)(u >> 16);
}
__device__ inline float bf2f(u16 h) {
    union { unsigned u; float f; } c; c.u = ((unsigned)h) << 16;
    return c.f;
}

// ---------------------------------------------------------------------------
// Pre-cast weights to bf16 (wq, wk -> hi; wv -> hi+lo). 1M floats each.
// ---------------------------------------------------------------------------
__global__ __launch_bounds__(256)
void precast_w(const float* __restrict__ wq, const float* __restrict__ wk,
               const float* __restrict__ wv, u16* __restrict__ Wq,
               u16* __restrict__ Wk, u16* __restrict__ Wvhi,
               u16* __restrict__ Wvlo)
{
    const int which = blockIdx.y;
    const float* src = (which == 0) ? wq : (which == 1) ? wk : wv;
    const size_t i = ((size_t)blockIdx.x * 256 + threadIdx.x) * 4;
    float4 xv = *(const float4*)&src[i];
    float xe[4] = {xv.x, xv.y, xv.z, xv.w};
    u16 h[4];
    #pragma unroll
    for (int e = 0; e < 4; ++e) h[e] = f2bf(xe[e]);
    ushort4 ph = make_ushort4(h[0], h[1], h[2], h[3]);
    if (which == 0)      *(ushort4*)&Wq[i]   = ph;
    else if (which == 1) *(ushort4*)&Wk[i]   = ph;
    else {
        *(ushort4*)&Wvhi[i] = ph;
        ushort4 pl;
        pl.x = f2bf(xe[0] - bf2f(h[0])); pl.y = f2bf(xe[1] - bf2f(h[1]));
        pl.z = f2bf(xe[2] - bf2f(h[2])); pl.w = f2bf(xe[3] - bf2f(h[3]));
        *(ushort4*)&Wvlo[i] = pl;
    }
}

// ---------------------------------------------------------------------------
// Projection GEMM via bf16 MFMA. X fp32 converted in-loop (hi, +lo for V);
// W read pre-cast bf16 (raw b128 copies into LDS). Q/K outputs natural
// [b,h,s,d]; V output TRANSPOSED [b,h,vd,s] hi+lo (ushort4 stores: C-layout
// rows quad*4+i are 4 consecutive s).
// ---------------------------------------------------------------------------
__global__ __launch_bounds__(256)
void proj_mfma(const float* __restrict__ Qi, const float* __restrict__ Ki,
               const float* __restrict__ Vi, const u16* __restrict__ Wq,
               const u16* __restrict__ Wk, const u16* __restrict__ Wvhi,
               const u16* __restrict__ Wvlo, u16* __restrict__ QP,
               u16* __restrict__ KP, u16* __restrict__ VThi,
               u16* __restrict__ VTlo)
{
    const int which = blockIdx.z;
    const bool isV  = (which == 2);
    const float* X  = (which == 0) ? Qi : (which == 1) ? Ki : Vi;
    const u16*  Wh  = (which == 0) ? Wq : (which == 1) ? Wk : Wvhi;

    __shared__ u16 Xhi[64][72], Whi_s[64][72];
    __shared__ u16 Xlo[64][72], Wlo_s[64][72];   // V only

    const int tid  = threadIdx.x;
    const int w    = tid >> 6;
    const int lane = tid & 63;
    const int quad = lane >> 4;
    const int lr   = lane & 15;
    const int r    = tid >> 2;          // loader row 0..63
    const int kb   = (tid & 3) * 16;    // loader k base (u16 units)
    const int m0   = blockIdx.y * 64;
    const int n0   = blockIdx.x * 64;

    f32x4 acc[4];
    #pragma unroll
    for (int n = 0; n < 4; ++n) acc[n] = (f32x4){0.f, 0.f, 0.f, 0.f};

    for (int k0 = 0; k0 < D_; k0 += 64) {
        float4 xv[4];
        #pragma unroll
        for (int c = 0; c < 4; ++c)
            xv[c] = *(const float4*)&X[(size_t)(m0 + r) * D_ + k0 + kb + c * 4];
        bf16x8 wh0 = *(const bf16x8*)&Wh[(size_t)(n0 + r) * D_ + k0 + kb];
        bf16x8 wh1 = *(const bf16x8*)&Wh[(size_t)(n0 + r) * D_ + k0 + kb + 8];
        bf16x8 wl0, wl1;
        if (isV) {
            wl0 = *(const bf16x8*)&Wvlo[(size_t)(n0 + r) * D_ + k0 + kb];
            wl1 = *(const bf16x8*)&Wvlo[(size_t)(n0 + r) * D_ + k0 + kb + 8];
        }
        __syncthreads();                 // prior iteration's frag reads done
        #pragma unroll
        for (int c = 0; c < 4; ++c) {
            float xe[4] = {xv[c].x, xv[c].y, xv[c].z, xv[c].w};
            u16 hx[4];
            #pragma unroll
            for (int e = 0; e < 4; ++e) hx[e] = f2bf(xe[e]);
            *(ushort4*)&Xhi[r][kb + c * 4] = make_ushort4(hx[0], hx[1], hx[2], hx[3]);
            if (isV) {
                ushort4 lx;
                lx.x = f2bf(xe[0] - bf2f(hx[0])); lx.y = f2bf(xe[1] - bf2f(hx[1]));
                lx.z = f2bf(xe[2] - bf2f(hx[2])); lx.w = f2bf(xe[3] - bf2f(hx[3]));
                *(ushort4*)&Xlo[r][kb + c * 4] = lx;
            }
        }
        *(bf16x8*)&Whi_s[r][kb]     = wh0;
        *(bf16x8*)&Whi_s[r][kb + 8] = wh1;
        if (isV) {
            *(bf16x8*)&Wlo_s[r][kb]     = wl0;
            *(bf16x8*)&Wlo_s[r][kb + 8] = wl1;
        }
        __syncthreads();

        #pragma unroll
        for (int ch = 0; ch < 2; ++ch) {
            bf16x8 ah = *(const bf16x8*)&Xhi[w * 16 + lr][ch * 32 + quad * 8];
            bf16x8 al;
            if (isV) al = *(const bf16x8*)&Xlo[w * 16 + lr][ch * 32 + quad * 8];
            #pragma unroll
            for (int n = 0; n < 4; ++n) {
                bf16x8 bh = *(const bf16x8*)&Whi_s[n * 16 + lr][ch * 32 + quad * 8];
                acc[n] = __builtin_amdgcn_mfma_f32_16x16x32_bf16(ah, bh, acc[n], 0, 0, 0);
                if (isV) {
                    bf16x8 bl = *(const bf16x8*)&Wlo_s[n * 16 + lr][ch * 32 + quad * 8];
                    acc[n] = __builtin_amdgcn_mfma_f32_16x16x32_bf16(ah, bl, acc[n], 0, 0, 0);
                    acc[n] = __builtin_amdgcn_mfma_f32_16x16x32_bf16(al, bh, acc[n], 0, 0, 0);
                }
            }
        }
    }

    const int h = n0 >> 6;               // tile spans exactly one head
    if (!isV) {
        u16* Pout = (which == 0) ? QP : KP;
        #pragma unroll
        for (int n = 0; n < 4; ++n)
            #pragma unroll
            for (int i = 0; i < 4; ++i) {
                int m  = m0 + w * 16 + quad * 4 + i;
                int b  = m >> 11;
                int s  = m & (S_ - 1);
                int hd = n * 16 + lr;
                Pout[(((size_t)b * H_ + h) * S_ + s) * HD_ + hd] = f2bf(acc[n][i]);
            }
    } else {
        int m = m0 + w * 16 + quad * 4;  // 4 consecutive s (same batch: 64|2048)
        int b = m >> 11;
        int s = m & (S_ - 1);
        #pragma unroll
        for (int n = 0; n < 4; ++n) {
            int vd = n * 16 + lr;
            ushort4 ph, pl;
            u16 hh[4];
            #pragma unroll
            for (int i = 0; i < 4; ++i) hh[i] = f2bf(acc[n][i]);
            ph = make_ushort4(hh[0], hh[1], hh[2], hh[3]);
            pl.x = f2bf(acc[n][0] - bf2f(hh[0])); pl.y = f2bf(acc[n][1] - bf2f(hh[1]));
            pl.z = f2bf(acc[n][2] - bf2f(hh[2])); pl.w = f2bf(acc[n][3] - bf2f(hh[3]));
            size_t base = (((size_t)b * H_ + h) * HD_ + vd) * S_ + s;
            *(ushort4*)&VThi[base] = ph;
            *(ushort4*)&VTlo[base] = pl;
        }
    }
}

// ---------------------------------------------------------------------------
// Per-64-key-tile V column sums from transposed V: TS[bh][t][vd]
// ---------------------------------------------------------------------------
__global__ __launch_bounds__(64)
void vtilesum_kernel(const u16* __restrict__ VThi, const u16* __restrict__ VTlo,
                     float* __restrict__ TS)
{
    const int t = blockIdx.x, bh = blockIdx.y, vd = threadIdx.x;
    const size_t base = ((size_t)bh * HD_ + vd) * S_ + t * 64;
    float acc = 0.f;
    #pragma unroll
    for (int j = 0; j < 64; ++j)
        acc += bf2f(VThi[base + j]) + bf2f(VTlo[base + j]);
    TS[((size_t)bh * NT_ + t) * HD_ + vd] = acc;
}

__global__ __launch_bounds__(64)
void vsuffix_kernel(const float* __restrict__ TS, float* __restrict__ SUF)
{
    const int bh = blockIdx.x, c = threadIdx.x;
    float acc = 0.f;
    SUF[((size_t)bh * (NT_ + 1) + NT_) * HD_ + c] = 0.f;
    for (int t = NT_ - 1; t >= 0; --t) {
        acc += TS[((size_t)bh * NT_ + t) * HD_ + c];
        SUF[((size_t)bh * (NT_ + 1) + t) * HD_ + c] = acc;
    }
}

// ---------------------------------------------------------------------------
// Barrier-free MFMA flash attention. K frags from KP [key][d] (contiguous),
// V frags from VT [vd][key] (contiguous) — direct global loads, L1/L2-served.
// LDS only for the band-local P round-trip (in-wave lgkmcnt ordering, no
// __syncthreads anywhere). Paired q-tiles (tq, NT-1-tq): uniform 33 iters.
// Softmax in exp2 domain. PV = Phi*Vhi + Phi*Vlo + Plo*Vhi.
// ---------------------------------------------------------------------------
__global__ __launch_bounds__(256)
void attn_mfma(const u16* __restrict__ QP, const u16* __restrict__ KP,
               const u16* __restrict__ VThi, const u16* __restrict__ VTlo,
               const float* __restrict__ SUF, float* __restrict__ OUT)
{
    const int pr = blockIdx.x;           // 0..15
    const int bh = blockIdx.y;
    const int b  = bh >> 4, h = bh & 15;

    __shared__ u16 Phi[4][16][72];       // [wave][q_local][key(+pad)]
    __shared__ u16 Plo[4][16][72];

    const int tid  = threadIdx.x;
    const int w    = tid >> 6;
    const int lane = tid & 63;
    const int quad = lane >> 4;
    const int lr   = lane & 15;

    const u16* Qb  = QP   + (size_t)bh * S_ * HD_;
    const u16* Kb  = KP   + (size_t)bh * S_ * HD_;
    const u16* Vhb = VThi + (size_t)bh * HD_ * S_;
    const u16* Vlb = VTlo + (size_t)bh * HD_ * S_;

    #pragma unroll
    for (int sub = 0; sub < 2; ++sub) {
        const int tq = sub ? pr : (NT_ - 1 - pr);
        const int q0 = tq * 64;

        bf16x8 qf[2];
        #pragma unroll
        for (int ch = 0; ch < 2; ++ch)
            qf[ch] = *(const bf16x8*)(Qb + (size_t)(q0 + w * 16 + lr) * HD_ +
                                      ch * 32 + quad * 8);

        f32x4 of[4];
        #pragma unroll
        for (int n = 0; n < 4; ++n) of[n] = (f32x4){0.f, 0.f, 0.f, 0.f};
        float m_i[4], l_i[4];
        #pragma unroll
        for (int i = 0; i < 4; ++i) { m_i[i] = -1e30f; l_i[i] = 0.f; }

        for (int t = 0; t <= tq; ++t) {
            const int k0t = t * 64;

            // ---- S = Q K^T, B-frags straight from global ----
            f32x4 sf[4];
            #pragma unroll
            for (int n = 0; n < 4; ++n) sf[n] = (f32x4){0.f, 0.f, 0.f, 0.f};
            #pragma unroll
            for (int ch = 0; ch < 2; ++ch)
                #pragma unroll
                for (int n = 0; n < 4; ++n) {
                    bf16x8 bk = *(const bf16x8*)(Kb +
                        (size_t)(k0t + n * 16 + lr) * HD_ + ch * 32 + quad * 8);
                    sf[n] = __builtin_amdgcn_mfma_f32_16x16x32_bf16(qf[ch], bk, sf[n], 0, 0, 0);
                }

            // ---- scale(log2 dom) + zero-mask (diagonal tile only) ----
            if (t == tq) {
                #pragma unroll
                for (int n = 0; n < 4; ++n)
                    #pragma unroll
                    for (int i = 0; i < 4; ++i) {
                        int ig = q0 + w * 16 + quad * 4 + i;
                        int jg = k0t + n * 16 + lr;
                        sf[n][i] = (jg <= ig) ? sf[n][i] * C2_ : 0.f;
                    }
            } else {
                #pragma unroll
                for (int n = 0; n < 4; ++n) sf[n] *= C2_;
            }

            // ---- online softmax, base 2 ----
            #pragma unroll
            for (int i = 0; i < 4; ++i) {
                float mx = fmaxf(fmaxf(sf[0][i], sf[1][i]), fmaxf(sf[2][i], sf[3][i]));
                mx = fmaxf(mx, __shfl_xor(mx, 1));
                mx = fmaxf(mx, __shfl_xor(mx, 2));
                mx = fmaxf(mx, __shfl_xor(mx, 4));
                mx = fmaxf(mx, __shfl_xor(mx, 8));
                float mn    = fmaxf(m_i[i], mx);
                float alpha = exp2f(m_i[i] - mn);
                m_i[i] = mn;
                float ps = 0.f;
                #pragma unroll
                for (int n = 0; n < 4; ++n) {
                    float p = exp2f(sf[n][i] - mn);
                    sf[n][i] = p;
                    ps += p;
                }
                ps += __shfl_xor(ps, 1); ps += __shfl_xor(ps, 2);
                ps += __shfl_xor(ps, 4); ps += __shfl_xor(ps, 8);
                l_i[i] = l_i[i] * alpha + ps;
                #pragma unroll
                for (int n = 0; n < 4; ++n) of[n][i] *= alpha;
            }

            // ---- P -> LDS (hi/lo), band-local: in-wave ordering only ----
            #pragma unroll
            for (int n = 0; n < 4; ++n)
                #pragma unroll
                for (int i = 0; i < 4; ++i) {
                    float p = sf[n][i];
                    u16 ph = f2bf(p);
                    Phi[w][quad * 4 + i][n * 16 + lr] = ph;
                    Plo[w][quad * 4 + i][n * 16 + lr] = f2bf(p - bf2f(ph));
                }

            // ---- O += P V, V-frags straight from global (VT layout) ----
            #pragma unroll
            for (int ch = 0; ch < 2; ++ch) {
                bf16x8 pah = *(const bf16x8*)&Phi[w][lr][ch * 32 + quad * 8];
                bf16x8 pal = *(const bf16x8*)&Plo[w][lr][ch * 32 + quad * 8];
                #pragma unroll
                for (int n = 0; n < 4; ++n) {
                    const size_t vb = (size_t)(n * 16 + lr) * S_ + k0t + ch * 32 + quad * 8;
                    bf16x8 bvh = *(const bf16x8*)(Vhb + vb);
                    bf16x8 bvl = *(const bf16x8*)(Vlb + vb);
                    of[n] = __builtin_amdgcn_mfma_f32_16x16x32_bf16(pah, bvh, of[n], 0, 0, 0);
                    of[n] = __builtin_amdgcn_mfma_f32_16x16x32_bf16(pah, bvl, of[n], 0, 0, 0);
                    of[n] = __builtin_amdgcn_mfma_f32_16x16x32_bf16(pal, bvh, of[n], 0, 0, 0);
                }
            }
        }

        // ---- masked-suffix contribution + normalize + store ----
        const int cnt = S_ - (q0 + 64);
        const float* suf = SUF + ((size_t)bh * (NT_ + 1) + (tq + 1)) * HD_;
        float sv[4];
        #pragma unroll
        for (int n = 0; n < 4; ++n) sv[n] = suf[n * 16 + lr];

        #pragma unroll
        for (int i = 0; i < 4; ++i) {
            float we    = exp2f(-m_i[i]);
            float denom = l_i[i] + we * (float)cnt;
            float inv   = 1.0f / denom;
            int   row   = q0 + w * 16 + quad * 4 + i;
            #pragma unroll
            for (int n = 0; n < 4; ++n) {
                int vd = n * 16 + lr;
                OUT[((size_t)b * S_ + row) * D_ + h * HD_ + vd] =
                    (of[n][i] + we * sv[n]) * inv;
            }
        }
    }
}

// ---------------------------------------------------------------------------
extern "C" void kernel_launch(void* const* d_in, const int* in_sizes, int n_in,
                              void* d_out, int out_size, void* d_ws, size_t ws_size,
                              hipStream_t stream)
{
    (void)in_sizes; (void)n_in; (void)out_size; (void)ws_size;
    const float* q  = (const float*)d_in[0];
    const float* k  = (const float*)d_in[1];
    const float* v  = (const float*)d_in[2];
    const float* wq = (const float*)d_in[3];
    const float* wk = (const float*)d_in[4];
    const float* wv = (const float*)d_in[5];
    float* out = (float*)d_out;

    const size_t PROJ = (size_t)B_ * H_ * S_ * HD_;     // 4,194,304 elems
    const size_t WSZ  = (size_t)D_ * D_;                // 1,048,576 elems
    u16* QP   = (u16*)d_ws;
    u16* KP   = QP + PROJ;
    u16* VThi = KP + PROJ;
    u16* VTlo = VThi + PROJ;
    u16* Wq   = VTlo + PROJ;
    u16* Wk   = Wq + WSZ;
    u16* Wvhi = Wk + WSZ;
    u16* Wvlo = Wvhi + WSZ;
    float* TS  = (float*)(Wvlo + WSZ);
    float* SUF = TS + (size_t)B_ * H_ * NT_ * HD_;

    precast_w<<<dim3(WSZ / 1024, 3), 256, 0, stream>>>(wq, wk, wv, Wq, Wk, Wvhi, Wvlo);
    proj_mfma<<<dim3(D_ / 64, (B_ * S_) / 64, 3), 256, 0, stream>>>(
        q, k, v, Wq, Wk, Wvhi, Wvlo, QP, KP, VThi, VTlo);
    vtilesum_kernel<<<dim3(NT_, B_ * H_), 64, 0, stream>>>(VThi, VTlo, TS);
    vsuffix_kernel<<<B_ * H_, 64, 0, stream>>>(TS, SUF);
    attn_mfma<<<dim3(NT_ / 2, B_ * H_), 256, 0, stream>>>(QP, KP, VThi, VTlo, SUF, out);
}

// Round 6
// 324.166 us; speedup vs baseline: 1.3241x; 1.3241x over previous
//
#include <hip/hip_runtime.h>
#include <math.h>

#define B_  2
#define S_  2048
#define D_  1024
#define H_  16
#define HD_ 64
#define NT_ (S_/64)          // 32 key tiles
#define C2_ (0.125f * 1.44269504088896f)   // scale * log2(e)

typedef __attribute__((ext_vector_type(8))) short bf16x8;
typedef __attribute__((ext_vector_type(4))) float f32x4;
typedef unsigned short u16;
typedef unsigned int   u32;

__device__ inline u16 f2bf(float f) {            // RNE
    union { float f; u32 u; } c; c.f = f;
    u32 u = c.u;
    u += 0x7fffu + ((u >> 16) & 1u);
    return (u16)(u >> 16);
}
__device__ inline float bf2f(u16 h) {
    union { u32 u; float f; } c; c.u = ((u32)h) << 16;
    return c.f;
}
__device__ inline u32 pack_bf_trunc(float a, float b) {  // [lo16=a, hi16=b]
    return (__float_as_uint(a) >> 16) | (__float_as_uint(b) & 0xFFFF0000u);
}
__device__ inline float trunc_hi(float a) {
    return __uint_as_float(__float_as_uint(a) & 0xFFFF0000u);
}

// ---------------------------------------------------------------------------
// Pre-cast: wq,wk -> bf16 hi; wv -> hi+lo; v -> hi+lo. z picks tensor.
// ---------------------------------------------------------------------------
__global__ __launch_bounds__(256)
void precast(const float* __restrict__ wq, const float* __restrict__ wk,
             const float* __restrict__ wv, const float* __restrict__ v,
             u16* __restrict__ Wq, u16* __restrict__ Wk,
             u16* __restrict__ Wvh, u16* __restrict__ Wvl,
             u16* __restrict__ Xvh, u16* __restrict__ Xvl)
{
    const int z = blockIdx.y;
    const size_t n = (z == 3) ? (size_t)B_ * S_ * D_ : (size_t)D_ * D_;
    const size_t i = ((size_t)blockIdx.x * 256 + threadIdx.x) * 4;
    if (i >= n) return;
    const float* src = (z == 0) ? wq : (z == 1) ? wk : (z == 2) ? wv : v;
    float4 xv = *(const float4*)&src[i];
    float xe[4] = {xv.x, xv.y, xv.z, xv.w};
    u16 h[4];
    #pragma unroll
    for (int e = 0; e < 4; ++e) h[e] = f2bf(xe[e]);
    ushort4 ph = make_ushort4(h[0], h[1], h[2], h[3]);
    if (z == 0)      *(ushort4*)&Wq[i] = ph;
    else if (z == 1) *(ushort4*)&Wk[i] = ph;
    else {
        ushort4 pl;
        pl.x = f2bf(xe[0] - bf2f(h[0])); pl.y = f2bf(xe[1] - bf2f(h[1]));
        pl.z = f2bf(xe[2] - bf2f(h[2])); pl.w = f2bf(xe[3] - bf2f(h[3]));
        if (z == 2) { *(ushort4*)&Wvh[i] = ph; *(ushort4*)&Wvl[i] = pl; }
        else        { *(ushort4*)&Xvh[i] = ph; *(ushort4*)&Xvl[i] = pl; }
    }
}

// ---------------------------------------------------------------------------
// Q/K projection: X fp32 (cvt in-loop, RNE), W pre-cast bf16 (b128 staging).
// 64x64 tile, 4 waves, BK=64. Output natural [b,h,s,hd]. LDS 18 KB.
// ---------------------------------------------------------------------------
__global__ __launch_bounds__(256)
void proj_qk(const float* __restrict__ Qi, const float* __restrict__ Ki,
             const u16* __restrict__ Wq, const u16* __restrict__ Wk,
             u16* __restrict__ QP, u16* __restrict__ KP)
{
    const int which = blockIdx.z;
    const float* X = which ? Ki : Qi;
    const u16*  Wh = which ? Wk : Wq;
    u16*        P  = which ? KP : QP;

    __shared__ u16 Xs[64][72], Ws[64][72];

    const int tid  = threadIdx.x;
    const int w    = tid >> 6;
    const int lane = tid & 63;
    const int quad = lane >> 4;
    const int lr   = lane & 15;
    const int r    = tid >> 2;
    const int cb   = (tid & 3) * 16;
    const int m0   = blockIdx.y * 64;
    const int n0   = blockIdx.x * 64;

    f32x4 acc[4];
    #pragma unroll
    for (int n = 0; n < 4; ++n) acc[n] = (f32x4){0.f, 0.f, 0.f, 0.f};

    for (int k0 = 0; k0 < D_; k0 += 64) {
        float4 xv[4];
        #pragma unroll
        for (int c = 0; c < 4; ++c)
            xv[c] = *(const float4*)&X[(size_t)(m0 + r) * D_ + k0 + cb + c * 4];
        bf16x8 wv = *(const bf16x8*)&Wh[(size_t)(n0 + r) * D_ + k0 + cb];
        bf16x8 wv2 = *(const bf16x8*)&Wh[(size_t)(n0 + r) * D_ + k0 + cb + 8];
        __syncthreads();
        #pragma unroll
        for (int c = 0; c < 4; ++c) {
            float xe[4] = {xv[c].x, xv[c].y, xv[c].z, xv[c].w};
            *(ushort4*)&Xs[r][cb + c * 4] =
                make_ushort4(f2bf(xe[0]), f2bf(xe[1]), f2bf(xe[2]), f2bf(xe[3]));
        }
        *(bf16x8*)&Ws[r][cb]     = wv;
        *(bf16x8*)&Ws[r][cb + 8] = wv2;
        __syncthreads();

        #pragma unroll
        for (int ch = 0; ch < 2; ++ch) {
            bf16x8 a = *(const bf16x8*)&Xs[w * 16 + lr][ch * 32 + quad * 8];
            #pragma unroll
            for (int n = 0; n < 4; ++n) {
                bf16x8 b = *(const bf16x8*)&Ws[n * 16 + lr][ch * 32 + quad * 8];
                acc[n] = __builtin_amdgcn_mfma_f32_16x16x32_bf16(a, b, acc[n], 0, 0, 0);
            }
        }
    }

    const int h = n0 >> 6;
    #pragma unroll
    for (int n = 0; n < 4; ++n)
        #pragma unroll
        for (int i = 0; i < 4; ++i) {
            int m  = m0 + w * 16 + quad * 4 + i;
            int b  = m >> 11;
            int s  = m & (S_ - 1);
            int hd = n * 16 + lr;
            P[(((size_t)b * H_ + h) * S_ + s) * HD_ + hd] = f2bf(acc[n][i]);
        }
}

// ---------------------------------------------------------------------------
// V projection: all inputs pre-cast bf16 hi/lo, pure b128 staging.
// 3 products (xh*wh + xh*wl + xl*wh). Output TRANSPOSED [b,h,vd,s] hi+lo.
// ---------------------------------------------------------------------------
__global__ __launch_bounds__(256)
void proj_v(const u16* __restrict__ Xvh, const u16* __restrict__ Xvl,
            const u16* __restrict__ Wvh, const u16* __restrict__ Wvl,
            u16* __restrict__ VThi, u16* __restrict__ VTlo)
{
    __shared__ u16 Xh[64][72], Wh[64][72], Xl[64][72], Wl[64][72];

    const int tid  = threadIdx.x;
    const int w    = tid >> 6;
    const int lane = tid & 63;
    const int quad = lane >> 4;
    const int lr   = lane & 15;
    const int r    = tid >> 2;
    const int cb   = (tid & 3) * 16;
    const int m0   = blockIdx.y * 64;
    const int n0   = blockIdx.x * 64;

    f32x4 acc[4];
    #pragma unroll
    for (int n = 0; n < 4; ++n) acc[n] = (f32x4){0.f, 0.f, 0.f, 0.f};

    for (int k0 = 0; k0 < D_; k0 += 64) {
        bf16x8 xh[2], xl[2], wh[2], wl[2];
        #pragma unroll
        for (int c = 0; c < 2; ++c) {
            xh[c] = *(const bf16x8*)&Xvh[(size_t)(m0 + r) * D_ + k0 + cb + c * 8];
            xl[c] = *(const bf16x8*)&Xvl[(size_t)(m0 + r) * D_ + k0 + cb + c * 8];
            wh[c] = *(const bf16x8*)&Wvh[(size_t)(n0 + r) * D_ + k0 + cb + c * 8];
            wl[c] = *(const bf16x8*)&Wvl[(size_t)(n0 + r) * D_ + k0 + cb + c * 8];
        }
        __syncthreads();
        #pragma unroll
        for (int c = 0; c < 2; ++c) {
            *(bf16x8*)&Xh[r][cb + c * 8] = xh[c];
            *(bf16x8*)&Xl[r][cb + c * 8] = xl[c];
            *(bf16x8*)&Wh[r][cb + c * 8] = wh[c];
            *(bf16x8*)&Wl[r][cb + c * 8] = wl[c];
        }
        __syncthreads();

        #pragma unroll
        for (int ch = 0; ch < 2; ++ch) {
            bf16x8 ah = *(const bf16x8*)&Xh[w * 16 + lr][ch * 32 + quad * 8];
            bf16x8 al = *(const bf16x8*)&Xl[w * 16 + lr][ch * 32 + quad * 8];
            #pragma unroll
            for (int n = 0; n < 4; ++n) {
                bf16x8 bh = *(const bf16x8*)&Wh[n * 16 + lr][ch * 32 + quad * 8];
                bf16x8 bl = *(const bf16x8*)&Wl[n * 16 + lr][ch * 32 + quad * 8];
                acc[n] = __builtin_amdgcn_mfma_f32_16x16x32_bf16(ah, bh, acc[n], 0, 0, 0);
                acc[n] = __builtin_amdgcn_mfma_f32_16x16x32_bf16(ah, bl, acc[n], 0, 0, 0);
                acc[n] = __builtin_amdgcn_mfma_f32_16x16x32_bf16(al, bh, acc[n], 0, 0, 0);
            }
        }
    }

    const int h = n0 >> 6;
    int m = m0 + w * 16 + quad * 4;       // 4 consecutive s
    int b = m >> 11;
    int s = m & (S_ - 1);
    #pragma unroll
    for (int n = 0; n < 4; ++n) {
        int vd = n * 16 + lr;
        u16 hh[4];
        #pragma unroll
        for (int i = 0; i < 4; ++i) hh[i] = f2bf(acc[n][i]);
        ushort4 ph = make_ushort4(hh[0], hh[1], hh[2], hh[3]);
        ushort4 pl;
        pl.x = f2bf(acc[n][0] - bf2f(hh[0])); pl.y = f2bf(acc[n][1] - bf2f(hh[1]));
        pl.z = f2bf(acc[n][2] - bf2f(hh[2])); pl.w = f2bf(acc[n][3] - bf2f(hh[3]));
        size_t base = (((size_t)b * H_ + h) * HD_ + vd) * S_ + s;
        *(ushort4*)&VThi[base] = ph;
        *(ushort4*)&VTlo[base] = pl;
    }
}

// ---------------------------------------------------------------------------
// V tile sums + suffix sums (for the masked-region analytic contribution)
// ---------------------------------------------------------------------------
__global__ __launch_bounds__(64)
void vtilesum_kernel(const u16* __restrict__ VThi, const u16* __restrict__ VTlo,
                     float* __restrict__ TS)
{
    const int t = blockIdx.x, bh = blockIdx.y, vd = threadIdx.x;
    const size_t base = ((size_t)bh * HD_ + vd) * S_ + t * 64;
    float acc = 0.f;
    #pragma unroll
    for (int j = 0; j < 64; ++j)
        acc += bf2f(VThi[base + j]) + bf2f(VTlo[base + j]);
    TS[((size_t)bh * NT_ + t) * HD_ + vd] = acc;
}

__global__ __launch_bounds__(64)
void vsuffix_kernel(const float* __restrict__ TS, float* __restrict__ SUF)
{
    const int bh = blockIdx.x, c = threadIdx.x;
    float acc = 0.f;
    SUF[((size_t)bh * (NT_ + 1) + NT_) * HD_ + c] = 0.f;
    for (int t = NT_ - 1; t >= 0; --t) {
        acc += TS[((size_t)bh * NT_ + t) * HD_ + c];
        SUF[((size_t)bh * (NT_ + 1) + t) * HD_ + c] = acc;
    }
}

// ---------------------------------------------------------------------------
// Transposed-score MFMA flash attention.
// S^T = K·Q^T  (A=K-frag [key][d], B=Q-frag [d][q]) -> C: col=q (lane&15),
// row=key (quad*4+reg). Each lane owns ONE q-row: softmax reductions are
// in-lane + 2 shfl_xor (16,32). P^T enters PV as B-frag via an LDS
// round-trip of 8 b32 writes / 4 b128 reads per wave.
// O^T = V^T·P^T (A=VT-frag [vd][key] from LDS-staged VT).
// K/VT tiles LDS-staged (shared by 4 waves), prefetched into regs.
// R6 fix: stage loaders cover BOTH 8-element chunks per 16-col group
// (R5 only filled half of each tile -> absmax 0.746).
// ---------------------------------------------------------------------------
__global__ __launch_bounds__(256)
void attn_mfma(const u16* __restrict__ QP, const u16* __restrict__ KP,
               const u16* __restrict__ VThi, const u16* __restrict__ VTlo,
               const float* __restrict__ SUF, float* __restrict__ OUT)
{
    const int tq = NT_ - 1 - (int)blockIdx.x;   // heavy first
    const int bh = blockIdx.y;
    const int b  = bh >> 4, h = bh & 15;
    const int q0 = tq * 64;

    __shared__ u16 Ks[64][72];       // [key][d]
    __shared__ u16 Vth[64][72];      // [vd][key]
    __shared__ u16 Vtl[64][72];
    __shared__ u16 Phi[4][16][72];   // [wave][q][key]  == P^T as B-frag source
    __shared__ u16 Plo[4][16][72];

    const int tid  = threadIdx.x;
    const int w    = tid >> 6;
    const int lane = tid & 63;
    const int quad = lane >> 4;
    const int lr   = lane & 15;
    const int r    = tid >> 2;          // stage row 0..63
    const int cb   = (tid & 3) * 16;    // stage col base (covers cb..cb+15)

    const u16* Qb  = QP   + (size_t)bh * S_ * HD_;
    const u16* Kb  = KP   + (size_t)bh * S_ * HD_;
    const u16* Vhb = VThi + (size_t)bh * HD_ * S_;
    const u16* Vlb = VTlo + (size_t)bh * HD_ * S_;

    // Q as B-frag: B[k=d][n=q], lane holds q=lr, d=quad*8+j
    bf16x8 qf[2];
    #pragma unroll
    for (int ch = 0; ch < 2; ++ch)
        qf[ch] = *(const bf16x8*)(Qb + (size_t)(q0 + w * 16 + lr) * HD_ +
                                  ch * 32 + quad * 8);

    f32x4 of[4];
    #pragma unroll
    for (int n = 0; n < 4; ++n) of[n] = (f32x4){0.f, 0.f, 0.f, 0.f};
    float m_i = -1e30f, l_i = 0.f;      // per-lane: one q-row each

    // prefetch tile 0 (both 8-elem chunks per 16-col group)
    bf16x8 kpre[2], vhpre[2], vlpre[2];
    #pragma unroll
    for (int c = 0; c < 2; ++c) {
        kpre[c]  = *(const bf16x8*)(Kb  + (size_t)r * HD_ + cb + c * 8);
        vhpre[c] = *(const bf16x8*)(Vhb + (size_t)r * S_ + cb + c * 8);
        vlpre[c] = *(const bf16x8*)(Vlb + (size_t)r * S_ + cb + c * 8);
    }

    for (int t = 0; t <= tq; ++t) {
        const int k0t = t * 64;
        __syncthreads();   // (A) prior iteration's tile reads done
        #pragma unroll
        for (int c = 0; c < 2; ++c) {
            *(bf16x8*)&Ks[r][cb + c * 8]  = kpre[c];
            *(bf16x8*)&Vth[r][cb + c * 8] = vhpre[c];
            *(bf16x8*)&Vtl[r][cb + c * 8] = vlpre[c];
        }
        __syncthreads();   // (B) tiles visible
        if (t < tq) {      // prefetch next (vmcnt hides behind compute)
            const int kn = k0t + 64;
            #pragma unroll
            for (int c = 0; c < 2; ++c) {
                kpre[c]  = *(const bf16x8*)(Kb  + (size_t)(kn + r) * HD_ + cb + c * 8);
                vhpre[c] = *(const bf16x8*)(Vhb + (size_t)r * S_ + kn + cb + c * 8);
                vlpre[c] = *(const bf16x8*)(Vlb + (size_t)r * S_ + kn + cb + c * 8);
            }
        }

        // ---- S^T = K Q^T ----
        f32x4 sf[4];
        #pragma unroll
        for (int f = 0; f < 4; ++f) sf[f] = (f32x4){0.f, 0.f, 0.f, 0.f};
        #pragma unroll
        for (int ch = 0; ch < 2; ++ch)
            #pragma unroll
            for (int f = 0; f < 4; ++f) {
                bf16x8 ak = *(const bf16x8*)&Ks[f * 16 + lr][ch * 32 + quad * 8];
                sf[f] = __builtin_amdgcn_mfma_f32_16x16x32_bf16(ak, qf[ch], sf[f], 0, 0, 0);
            }

        // ---- scale (log2 domain) + zero-mask (diagonal tile only) ----
        const int ig = q0 + w * 16 + lr;    // this lane's q row
        if (t == tq) {
            #pragma unroll
            for (int f = 0; f < 4; ++f)
                #pragma unroll
                for (int i = 0; i < 4; ++i) {
                    int jg = k0t + f * 16 + quad * 4 + i;
                    sf[f][i] = (jg <= ig) ? sf[f][i] * C2_ : 0.f;
                }
        } else {
            #pragma unroll
            for (int f = 0; f < 4; ++f) sf[f] *= C2_;
        }

        // ---- online softmax (base 2): in-lane 16 + 2 shfls ----
        float mx = fmaxf(fmaxf(fmaxf(sf[0][0], sf[0][1]), fmaxf(sf[0][2], sf[0][3])),
                         fmaxf(fmaxf(sf[1][0], sf[1][1]), fmaxf(sf[1][2], sf[1][3])));
        mx = fmaxf(mx,
             fmaxf(fmaxf(fmaxf(sf[2][0], sf[2][1]), fmaxf(sf[2][2], sf[2][3])),
                   fmaxf(fmaxf(sf[3][0], sf[3][1]), fmaxf(sf[3][2], sf[3][3]))));
        mx = fmaxf(mx, __shfl_xor(mx, 16));
        mx = fmaxf(mx, __shfl_xor(mx, 32));
        float mn    = fmaxf(m_i, mx);
        float alpha = exp2f(m_i - mn);
        m_i = mn;
        float ps = 0.f;
        #pragma unroll
        for (int f = 0; f < 4; ++f)
            #pragma unroll
            for (int i = 0; i < 4; ++i) {
                float p = exp2f(sf[f][i] - mn);
                sf[f][i] = p;
                ps += p;
            }
        ps += __shfl_xor(ps, 16);
        ps += __shfl_xor(ps, 32);
        l_i = l_i * alpha + ps;
        #pragma unroll
        for (int n = 0; n < 4; ++n) of[n] *= alpha;

        // ---- P^T -> LDS: hi truncated, lo carries the residual ----
        #pragma unroll
        for (int f = 0; f < 4; ++f) {
            float p0 = sf[f][0], p1 = sf[f][1], p2 = sf[f][2], p3 = sf[f][3];
            *(u32*)&Phi[w][lr][f * 16 + quad * 4]     = pack_bf_trunc(p0, p1);
            *(u32*)&Phi[w][lr][f * 16 + quad * 4 + 2] = pack_bf_trunc(p2, p3);
            *(u32*)&Plo[w][lr][f * 16 + quad * 4]     =
                pack_bf_trunc(p0 - trunc_hi(p0), p1 - trunc_hi(p1));
            *(u32*)&Plo[w][lr][f * 16 + quad * 4 + 2] =
                pack_bf_trunc(p2 - trunc_hi(p2), p3 - trunc_hi(p3));
        }

        // ---- O^T += V^T P^T  (in-wave LDS ordering; no barrier needed) ----
        #pragma unroll
        for (int ch = 0; ch < 2; ++ch) {
            bf16x8 pbh = *(const bf16x8*)&Phi[w][lr][ch * 32 + quad * 8];
            bf16x8 pbl = *(const bf16x8*)&Plo[w][lr][ch * 32 + quad * 8];
            #pragma unroll
            for (int n = 0; n < 4; ++n) {
                bf16x8 avh = *(const bf16x8*)&Vth[n * 16 + lr][ch * 32 + quad * 8];
                bf16x8 avl = *(const bf16x8*)&Vtl[n * 16 + lr][ch * 32 + quad * 8];
                of[n] = __builtin_amdgcn_mfma_f32_16x16x32_bf16(avh, pbh, of[n], 0, 0, 0);
                of[n] = __builtin_amdgcn_mfma_f32_16x16x32_bf16(avh, pbl, of[n], 0, 0, 0);
                of[n] = __builtin_amdgcn_mfma_f32_16x16x32_bf16(avl, pbh, of[n], 0, 0, 0);
            }
        }
    }

    // ---- masked-suffix contribution + normalize + store (float4) ----
    const int cnt = S_ - (q0 + 64);
    const float* suf = SUF + ((size_t)bh * (NT_ + 1) + (tq + 1)) * HD_;
    float we    = exp2f(-m_i);
    float denom = l_i + we * (float)cnt;
    float inv   = 1.0f / denom;
    const int srow = q0 + w * 16 + lr;
    #pragma unroll
    for (int n = 0; n < 4; ++n) {
        float4 sv = *(const float4*)&suf[n * 16 + quad * 4];
        float4 ov;
        ov.x = (of[n][0] + we * sv.x) * inv;
        ov.y = (of[n][1] + we * sv.y) * inv;
        ov.z = (of[n][2] + we * sv.z) * inv;
        ov.w = (of[n][3] + we * sv.w) * inv;
        *(float4*)&OUT[((size_t)b * S_ + srow) * D_ + h * HD_ + n * 16 + quad * 4] = ov;
    }
}

// ---------------------------------------------------------------------------
extern "C" void kernel_launch(void* const* d_in, const int* in_sizes, int n_in,
                              void* d_out, int out_size, void* d_ws, size_t ws_size,
                              hipStream_t stream)
{
    (void)in_sizes; (void)n_in; (void)out_size; (void)ws_size;
    const float* q  = (const float*)d_in[0];
    const float* k  = (const float*)d_in[1];
    const float* v  = (const float*)d_in[2];
    const float* wq = (const float*)d_in[3];
    const float* wk = (const float*)d_in[4];
    const float* wv = (const float*)d_in[5];
    float* out = (float*)d_out;

    const size_t PROJ = (size_t)B_ * H_ * S_ * HD_;     // 4,194,304 elems
    const size_t WSZ  = (size_t)D_ * D_;                // 1,048,576 elems
    u16* QP   = (u16*)d_ws;
    u16* KP   = QP + PROJ;
    u16* VThi = KP + PROJ;
    u16* VTlo = VThi + PROJ;
    u16* Wq   = VTlo + PROJ;
    u16* Wk   = Wq + WSZ;
    u16* Wvh  = Wk + WSZ;
    u16* Wvl  = Wvh + WSZ;
    u16* Xvh  = Wvl + WSZ;
    u16* Xvl  = Xvh + PROJ;
    float* TS  = (float*)(Xvl + PROJ);
    float* SUF = TS + (size_t)B_ * H_ * NT_ * HD_;

    precast<<<dim3(PROJ / 1024, 4), 256, 0, stream>>>(wq, wk, wv, v,
                                                      Wq, Wk, Wvh, Wvl, Xvh, Xvl);
    proj_qk<<<dim3(D_ / 64, (B_ * S_) / 64, 2), 256, 0, stream>>>(
        q, k, Wq, Wk, QP, KP);
    proj_v<<<dim3(D_ / 64, (B_ * S_) / 64), 256, 0, stream>>>(
        Xvh, Xvl, Wvh, Wvl, VThi, VTlo);
    vtilesum_kernel<<<dim3(NT_, B_ * H_), 64, 0, stream>>>(VThi, VTlo, TS);
    vsuffix_kernel<<<B_ * H_, 64, 0, stream>>>(TS, SUF);
    attn_mfma<<<dim3(NT_, B_ * H_), 256, 0, stream>>>(QP, KP, VThi, VTlo, SUF, out);
}

// Round 7
// 269.614 us; speedup vs baseline: 1.5920x; 1.2023x over previous
//
#include <hip/hip_runtime.h>
#include <math.h>

#define B_  2
#define S_  2048
#define D_  1024
#define H_  16
#define HD_ 64
#define NT_ (S_/64)          // 32 key tiles
#define C2_ (0.125f * 1.44269504088896f)   // scale * log2(e)

typedef __attribute__((ext_vector_type(8))) short bf16x8;
typedef __attribute__((ext_vector_type(8))) _Float16 f16x8;
typedef __attribute__((ext_vector_type(4))) float f32x4;
typedef unsigned short u16;
typedef unsigned int   u32;

__device__ inline u16 f2bf(float f) {            // RNE fp32->bf16
    union { float f; u32 u; } c; c.f = f;
    u32 u = c.u;
    u += 0x7fffu + ((u >> 16) & 1u);
    return (u16)(u >> 16);
}
__device__ inline float bf2f(u16 h) {
    union { u32 u; float f; } c; c.u = ((u32)h) << 16;
    return c.f;
}
__device__ inline u16 f2h(float f) {             // RNE fp32->fp16 (HW cvt)
    union { _Float16 h; u16 u; } c; c.h = (_Float16)f;
    return c.u;
}
__device__ inline float h2f(u16 h) {
    union { u16 u; _Float16 h; } c; c.u = h;
    return (float)c.h;
}
__device__ inline u32 pack_h2(float a, float b) {  // [lo16=h(a), hi16=h(b)]
    return (u32)f2h(a) | ((u32)f2h(b) << 16);
}

// ---------------------------------------------------------------------------
// Pre-cast: z=0 wq->bf16, z=1 wk, z=2 wv->hi+lo, z=3 v->hi+lo,
//           z=4 q->bf16, z=5 k->bf16
// ---------------------------------------------------------------------------
__global__ __launch_bounds__(256)
void precast(const float* __restrict__ wq, const float* __restrict__ wk,
             const float* __restrict__ wv, const float* __restrict__ v,
             const float* __restrict__ q, const float* __restrict__ k,
             u16* __restrict__ Wq, u16* __restrict__ Wk,
             u16* __restrict__ Wvh, u16* __restrict__ Wvl,
             u16* __restrict__ Xvh, u16* __restrict__ Xvl,
             u16* __restrict__ Xq, u16* __restrict__ Xk)
{
    const int z = blockIdx.y;
    const size_t n = (z >= 3) ? (size_t)B_ * S_ * D_ : (size_t)D_ * D_;
    const size_t i = ((size_t)blockIdx.x * 256 + threadIdx.x) * 4;
    if (i >= n) return;
    const float* src = (z == 0) ? wq : (z == 1) ? wk : (z == 2) ? wv
                     : (z == 3) ? v  : (z == 4) ? q  : k;
    float4 xv = *(const float4*)&src[i];
    float xe[4] = {xv.x, xv.y, xv.z, xv.w};
    u16 h[4];
    #pragma unroll
    for (int e = 0; e < 4; ++e) h[e] = f2bf(xe[e]);
    ushort4 ph = make_ushort4(h[0], h[1], h[2], h[3]);
    if (z == 0)      *(ushort4*)&Wq[i] = ph;
    else if (z == 1) *(ushort4*)&Wk[i] = ph;
    else if (z == 4) *(ushort4*)&Xq[i] = ph;
    else if (z == 5) *(ushort4*)&Xk[i] = ph;
    else {
        ushort4 pl;
        pl.x = f2bf(xe[0] - bf2f(h[0])); pl.y = f2bf(xe[1] - bf2f(h[1]));
        pl.z = f2bf(xe[2] - bf2f(h[2])); pl.w = f2bf(xe[3] - bf2f(h[3]));
        if (z == 2) { *(ushort4*)&Wvh[i] = ph; *(ushort4*)&Wvl[i] = pl; }
        else        { *(ushort4*)&Xvh[i] = ph; *(ushort4*)&Xvl[i] = pl; }
    }
}

// ---------------------------------------------------------------------------
// Q/K projection, 128x128 tile, 4 waves, BK=64, 2x8 register-blocked
// 16x16x32 frags (A-reads x8 reuse, B-reads x2). Pure b128 staging (inputs
// pre-cast bf16). Output [b,h,s,hd] bf16.
// ---------------------------------------------------------------------------
__global__ __launch_bounds__(256)
void proj_qk(const u16* __restrict__ Xq, const u16* __restrict__ Xk,
             const u16* __restrict__ Wq, const u16* __restrict__ Wk,
             u16* __restrict__ QP, u16* __restrict__ KP)
{
    const int which = blockIdx.z;
    const u16* X = which ? Xk : Xq;
    const u16* W = which ? Wk : Wq;
    u16*       P = which ? KP : QP;

    __shared__ u16 Xs[128][72];   // [m][k], rows 144 B (16B-aligned)
    __shared__ u16 Ws[128][72];   // [n][k]

    const int tid  = threadIdx.x;
    const int w    = tid >> 6;
    const int lane = tid & 63;
    const int quad = lane >> 4;
    const int lr   = lane & 15;
    const int rr   = tid >> 1;          // loader row 0..127
    const int kb   = (tid & 1) * 32;    // loader k half
    const int m0   = blockIdx.y * 128;
    const int n0   = blockIdx.x * 128;

    f32x4 acc[2][8];
    #pragma unroll
    for (int i = 0; i < 2; ++i)
        #pragma unroll
        for (int j = 0; j < 8; ++j) acc[i][j] = (f32x4){0.f, 0.f, 0.f, 0.f};

    for (int k0 = 0; k0 < D_; k0 += 64) {
        bf16x8 xv[4], wv[4];
        #pragma unroll
        for (int c = 0; c < 4; ++c) {
            xv[c] = *(const bf16x8*)&X[(size_t)(m0 + rr) * D_ + k0 + kb + c * 8];
            wv[c] = *(const bf16x8*)&W[(size_t)(n0 + rr) * D_ + k0 + kb + c * 8];
        }
        __syncthreads();
        #pragma unroll
        for (int c = 0; c < 4; ++c) {
            *(bf16x8*)&Xs[rr][kb + c * 8] = xv[c];
            *(bf16x8*)&Ws[rr][kb + c * 8] = wv[c];
        }
        __syncthreads();

        #pragma unroll
        for (int ch = 0; ch < 2; ++ch) {
            bf16x8 a[2];
            #pragma unroll
            for (int i = 0; i < 2; ++i)
                a[i] = *(const bf16x8*)&Xs[w * 32 + i * 16 + lr][ch * 32 + quad * 8];
            #pragma unroll
            for (int j = 0; j < 8; ++j) {
                bf16x8 b = *(const bf16x8*)&Ws[j * 16 + lr][ch * 32 + quad * 8];
                #pragma unroll
                for (int i = 0; i < 2; ++i)
                    acc[i][j] = __builtin_amdgcn_mfma_f32_16x16x32_bf16(a[i], b, acc[i][j], 0, 0, 0);
            }
        }
    }

    #pragma unroll
    for (int i = 0; i < 2; ++i)
        #pragma unroll
        for (int j = 0; j < 8; ++j) {
            int n  = n0 + j * 16 + lr;
            int h  = n >> 6, hd = n & 63;
            #pragma unroll
            for (int r = 0; r < 4; ++r) {
                int m = m0 + w * 32 + i * 16 + quad * 4 + r;
                int b = m >> 11, s = m & (S_ - 1);
                P[(((size_t)b * H_ + h) * S_ + s) * HD_ + hd] = f2bf(acc[i][j][r]);
            }
        }
}

// ---------------------------------------------------------------------------
// V projection, 128x128 tile, bf16 hi/lo 3-product, output fp16 TRANSPOSED
// [b,h,vd,s].
// ---------------------------------------------------------------------------
__global__ __launch_bounds__(256)
void proj_v(const u16* __restrict__ Xvh, const u16* __restrict__ Xvl,
            const u16* __restrict__ Wvh, const u16* __restrict__ Wvl,
            u16* __restrict__ VT)
{
    __shared__ u16 Xh[128][72], Xl[128][72], Wh[128][72], Wl[128][72];

    const int tid  = threadIdx.x;
    const int w    = tid >> 6;
    const int lane = tid & 63;
    const int quad = lane >> 4;
    const int lr   = lane & 15;
    const int rr   = tid >> 1;
    const int kb   = (tid & 1) * 32;
    const int m0   = blockIdx.y * 128;
    const int n0   = blockIdx.x * 128;

    f32x4 acc[2][8];
    #pragma unroll
    for (int i = 0; i < 2; ++i)
        #pragma unroll
        for (int j = 0; j < 8; ++j) acc[i][j] = (f32x4){0.f, 0.f, 0.f, 0.f};

    for (int k0 = 0; k0 < D_; k0 += 64) {
        bf16x8 xh[4], xl[4], wh[4], wl[4];
        #pragma unroll
        for (int c = 0; c < 4; ++c) {
            xh[c] = *(const bf16x8*)&Xvh[(size_t)(m0 + rr) * D_ + k0 + kb + c * 8];
            xl[c] = *(const bf16x8*)&Xvl[(size_t)(m0 + rr) * D_ + k0 + kb + c * 8];
            wh[c] = *(const bf16x8*)&Wvh[(size_t)(n0 + rr) * D_ + k0 + kb + c * 8];
            wl[c] = *(const bf16x8*)&Wvl[(size_t)(n0 + rr) * D_ + k0 + kb + c * 8];
        }
        __syncthreads();
        #pragma unroll
        for (int c = 0; c < 4; ++c) {
            *(bf16x8*)&Xh[rr][kb + c * 8] = xh[c];
            *(bf16x8*)&Xl[rr][kb + c * 8] = xl[c];
            *(bf16x8*)&Wh[rr][kb + c * 8] = wh[c];
            *(bf16x8*)&Wl[rr][kb + c * 8] = wl[c];
        }
        __syncthreads();

        #pragma unroll
        for (int ch = 0; ch < 2; ++ch) {
            bf16x8 ah[2], al[2];
            #pragma unroll
            for (int i = 0; i < 2; ++i) {
                ah[i] = *(const bf16x8*)&Xh[w * 32 + i * 16 + lr][ch * 32 + quad * 8];
                al[i] = *(const bf16x8*)&Xl[w * 32 + i * 16 + lr][ch * 32 + quad * 8];
            }
            #pragma unroll
            for (int j = 0; j < 8; ++j) {
                bf16x8 bh = *(const bf16x8*)&Wh[j * 16 + lr][ch * 32 + quad * 8];
                bf16x8 bl = *(const bf16x8*)&Wl[j * 16 + lr][ch * 32 + quad * 8];
                #pragma unroll
                for (int i = 0; i < 2; ++i) {
                    acc[i][j] = __builtin_amdgcn_mfma_f32_16x16x32_bf16(ah[i], bh, acc[i][j], 0, 0, 0);
                    acc[i][j] = __builtin_amdgcn_mfma_f32_16x16x32_bf16(ah[i], bl, acc[i][j], 0, 0, 0);
                    acc[i][j] = __builtin_amdgcn_mfma_f32_16x16x32_bf16(al[i], bh, acc[i][j], 0, 0, 0);
                }
            }
        }
    }

    #pragma unroll
    for (int i = 0; i < 2; ++i)
        #pragma unroll
        for (int j = 0; j < 8; ++j) {
            int n  = n0 + j * 16 + lr;
            int h  = n >> 6, vd = n & 63;
            int m  = m0 + w * 32 + i * 16 + quad * 4;   // 4 consecutive s
            int b  = m >> 11, s = m & (S_ - 1);
            ushort4 pv = make_ushort4(f2h(acc[i][j][0]), f2h(acc[i][j][1]),
                                      f2h(acc[i][j][2]), f2h(acc[i][j][3]));
            *(ushort4*)&VT[(((size_t)b * H_ + h) * HD_ + vd) * S_ + s] = pv;
        }
}

// ---------------------------------------------------------------------------
// V tile sums (fp16 VT) + suffix sums
// ---------------------------------------------------------------------------
__global__ __launch_bounds__(64)
void vtilesum_kernel(const u16* __restrict__ VT, float* __restrict__ TS)
{
    const int t = blockIdx.x, bh = blockIdx.y, vd = threadIdx.x;
    const size_t base = ((size_t)bh * HD_ + vd) * S_ + t * 64;
    float acc = 0.f;
    #pragma unroll
    for (int j = 0; j < 64; ++j) acc += h2f(VT[base + j]);
    TS[((size_t)bh * NT_ + t) * HD_ + vd] = acc;
}

__global__ __launch_bounds__(64)
void vsuffix_kernel(const float* __restrict__ TS, float* __restrict__ SUF)
{
    const int bh = blockIdx.x, c = threadIdx.x;
    float acc = 0.f;
    SUF[((size_t)bh * (NT_ + 1) + NT_) * HD_ + c] = 0.f;
    for (int t = NT_ - 1; t >= 0; --t) {
        acc += TS[((size_t)bh * NT_ + t) * HD_ + c];
        SUF[((size_t)bh * (NT_ + 1) + t) * HD_ + c] = acc;
    }
}

// ---------------------------------------------------------------------------
// Transposed-score MFMA flash attention (R6 structure) with fp16 single-
// product PV: V fp16 (from proj_v), P cast fp16 RNE. Stage = Ks(bf16) +
// Vth(fp16) only; P round-trip single. LDS 27.6 KB -> 5 blocks/CU.
// ---------------------------------------------------------------------------
__global__ __launch_bounds__(256)
void attn_mfma(const u16* __restrict__ QP, const u16* __restrict__ KP,
               const u16* __restrict__ VT, const float* __restrict__ SUF,
               float* __restrict__ OUT)
{
    const int tq = NT_ - 1 - (int)blockIdx.x;   // heavy first
    const int bh = blockIdx.y;
    const int b  = bh >> 4, h = bh & 15;
    const int q0 = tq * 64;

    __shared__ u16 Ks[64][72];       // [key][d]   bf16
    __shared__ u16 Vth[64][72];      // [vd][key]  fp16
    __shared__ u16 Phi[4][16][72];   // [wave][q][key] fp16

    const int tid  = threadIdx.x;
    const int w    = tid >> 6;
    const int lane = tid & 63;
    const int quad = lane >> 4;
    const int lr   = lane & 15;
    const int r    = tid >> 2;          // stage row 0..63
    const int cb   = (tid & 3) * 16;    // stage col base (cb..cb+15)

    const u16* Qb = QP + (size_t)bh * S_ * HD_;
    const u16* Kb = KP + (size_t)bh * S_ * HD_;
    const u16* Vb = VT + (size_t)bh * HD_ * S_;

    bf16x8 qf[2];
    #pragma unroll
    for (int ch = 0; ch < 2; ++ch)
        qf[ch] = *(const bf16x8*)(Qb + (size_t)(q0 + w * 16 + lr) * HD_ +
                                  ch * 32 + quad * 8);

    f32x4 of[4];
    #pragma unroll
    for (int n = 0; n < 4; ++n) of[n] = (f32x4){0.f, 0.f, 0.f, 0.f};
    float m_i = -1e30f, l_i = 0.f;

    bf16x8 kpre[2], vpre[2];
    #pragma unroll
    for (int c = 0; c < 2; ++c) {
        kpre[c] = *(const bf16x8*)(Kb + (size_t)r * HD_ + cb + c * 8);
        vpre[c] = *(const bf16x8*)(Vb + (size_t)r * S_ + cb + c * 8);
    }

    for (int t = 0; t <= tq; ++t) {
        const int k0t = t * 64;
        __syncthreads();   // (A) prior iteration's tile reads done
        #pragma unroll
        for (int c = 0; c < 2; ++c) {
            *(bf16x8*)&Ks[r][cb + c * 8]  = kpre[c];
            *(bf16x8*)&Vth[r][cb + c * 8] = vpre[c];
        }
        __syncthreads();   // (B) tiles visible
        if (t < tq) {
            const int kn = k0t + 64;
            #pragma unroll
            for (int c = 0; c < 2; ++c) {
                kpre[c] = *(const bf16x8*)(Kb + (size_t)(kn + r) * HD_ + cb + c * 8);
                vpre[c] = *(const bf16x8*)(Vb + (size_t)r * S_ + kn + cb + c * 8);
            }
        }

        // ---- S^T = K Q^T ----
        f32x4 sf[4];
        #pragma unroll
        for (int f = 0; f < 4; ++f) sf[f] = (f32x4){0.f, 0.f, 0.f, 0.f};
        #pragma unroll
        for (int ch = 0; ch < 2; ++ch)
            #pragma unroll
            for (int f = 0; f < 4; ++f) {
                bf16x8 ak = *(const bf16x8*)&Ks[f * 16 + lr][ch * 32 + quad * 8];
                sf[f] = __builtin_amdgcn_mfma_f32_16x16x32_bf16(ak, qf[ch], sf[f], 0, 0, 0);
            }

        // ---- scale (log2 domain) + zero-mask (diagonal tile only) ----
        const int ig = q0 + w * 16 + lr;
        if (t == tq) {
            #pragma unroll
            for (int f = 0; f < 4; ++f)
                #pragma unroll
                for (int i = 0; i < 4; ++i) {
                    int jg = k0t + f * 16 + quad * 4 + i;
                    sf[f][i] = (jg <= ig) ? sf[f][i] * C2_ : 0.f;
                }
        } else {
            #pragma unroll
            for (int f = 0; f < 4; ++f) sf[f] *= C2_;
        }

        // ---- online softmax (base 2): in-lane + 2 shfls ----
        float mx = fmaxf(fmaxf(fmaxf(sf[0][0], sf[0][1]), fmaxf(sf[0][2], sf[0][3])),
                         fmaxf(fmaxf(sf[1][0], sf[1][1]), fmaxf(sf[1][2], sf[1][3])));
        mx = fmaxf(mx,
             fmaxf(fmaxf(fmaxf(sf[2][0], sf[2][1]), fmaxf(sf[2][2], sf[2][3])),
                   fmaxf(fmaxf(sf[3][0], sf[3][1]), fmaxf(sf[3][2], sf[3][3]))));
        mx = fmaxf(mx, __shfl_xor(mx, 16));
        mx = fmaxf(mx, __shfl_xor(mx, 32));
        float mn    = fmaxf(m_i, mx);
        float alpha = exp2f(m_i - mn);
        m_i = mn;
        float ps = 0.f;
        #pragma unroll
        for (int f = 0; f < 4; ++f)
            #pragma unroll
            for (int i = 0; i < 4; ++i) {
                float p = exp2f(sf[f][i] - mn);
                sf[f][i] = p;
                ps += p;
            }
        ps += __shfl_xor(ps, 16);
        ps += __shfl_xor(ps, 32);
        l_i = l_i * alpha + ps;
        #pragma unroll
        for (int n = 0; n < 4; ++n) of[n] *= alpha;

        // ---- P -> LDS as fp16 (single) ----
        #pragma unroll
        for (int f = 0; f < 4; ++f) {
            *(u32*)&Phi[w][lr][f * 16 + quad * 4]     = pack_h2(sf[f][0], sf[f][1]);
            *(u32*)&Phi[w][lr][f * 16 + quad * 4 + 2] = pack_h2(sf[f][2], sf[f][3]);
        }

        // ---- O^T += V^T P^T  (fp16 MFMA, in-wave LDS ordering) ----
        #pragma unroll
        for (int ch = 0; ch < 2; ++ch) {
            f16x8 pb = *(const f16x8*)&Phi[w][lr][ch * 32 + quad * 8];
            #pragma unroll
            for (int n = 0; n < 4; ++n) {
                f16x8 av = *(const f16x8*)&Vth[n * 16 + lr][ch * 32 + quad * 8];
                of[n] = __builtin_amdgcn_mfma_f32_16x16x32_f16(av, pb, of[n], 0, 0, 0);
            }
        }
    }

    // ---- masked-suffix contribution + normalize + store (float4) ----
    const int cnt = S_ - (q0 + 64);
    const float* suf = SUF + ((size_t)bh * (NT_ + 1) + (tq + 1)) * HD_;
    float we    = exp2f(-m_i);
    float denom = l_i + we * (float)cnt;
    float inv   = 1.0f / denom;
    const int srow = q0 + w * 16 + lr;
    #pragma unroll
    for (int n = 0; n < 4; ++n) {
        float4 sv = *(const float4*)&suf[n * 16 + quad * 4];
        float4 ov;
        ov.x = (of[n][0] + we * sv.x) * inv;
        ov.y = (of[n][1] + we * sv.y) * inv;
        ov.z = (of[n][2] + we * sv.z) * inv;
        ov.w = (of[n][3] + we * sv.w) * inv;
        *(float4*)&OUT[((size_t)b * S_ + srow) * D_ + h * HD_ + n * 16 + quad * 4] = ov;
    }
}

// ---------------------------------------------------------------------------
extern "C" void kernel_launch(void* const* d_in, const int* in_sizes, int n_in,
                              void* d_out, int out_size, void* d_ws, size_t ws_size,
                              hipStream_t stream)
{
    (void)in_sizes; (void)n_in; (void)out_size; (void)ws_size;
    const float* q  = (const float*)d_in[0];
    const float* k  = (const float*)d_in[1];
    const float* v  = (const float*)d_in[2];
    const float* wq = (const float*)d_in[3];
    const float* wk = (const float*)d_in[4];
    const float* wv = (const float*)d_in[5];
    float* out = (float*)d_out;

    const size_t PROJ = (size_t)B_ * H_ * S_ * HD_;     // 4,194,304 elems
    const size_t WSZ  = (size_t)D_ * D_;                // 1,048,576 elems
    u16* QP  = (u16*)d_ws;
    u16* KP  = QP + PROJ;
    u16* VT  = KP + PROJ;
    u16* Xvh = VT + PROJ;
    u16* Xvl = Xvh + PROJ;
    u16* Xq  = Xvl + PROJ;
    u16* Xk  = Xq + PROJ;
    u16* Wq  = Xk + PROJ;
    u16* Wk  = Wq + WSZ;
    u16* Wvh = Wk + WSZ;
    u16* Wvl = Wvh + WSZ;
    float* TS  = (float*)(Wvl + WSZ);
    float* SUF = TS + (size_t)B_ * H_ * NT_ * HD_;

    precast<<<dim3(PROJ / 1024, 6), 256, 0, stream>>>(
        wq, wk, wv, v, q, k, Wq, Wk, Wvh, Wvl, Xvh, Xvl, Xq, Xk);
    proj_qk<<<dim3(D_ / 128, (B_ * S_) / 128, 2), 256, 0, stream>>>(
        Xq, Xk, Wq, Wk, QP, KP);
    proj_v<<<dim3(D_ / 128, (B_ * S_) / 128), 256, 0, stream>>>(
        Xvh, Xvl, Wvh, Wvl, VT);
    vtilesum_kernel<<<dim3(NT_, B_ * H_), 64, 0, stream>>>(VT, TS);
    vsuffix_kernel<<<B_ * H_, 64, 0, stream>>>(TS, SUF);
    attn_mfma<<<dim3(NT_, B_ * H_), 256, 0, stream>>>(QP, KP, VT, SUF, out);
}

// Round 8
// 225.125 us; speedup vs baseline: 1.9066x; 1.1976x over previous
//
#include <hip/hip_runtime.h>
#include <math.h>

#define B_  2
#define S_  2048
#define D_  1024
#define H_  16
#define HD_ 64
#define NT_ (S_/64)          // 32 key tiles
#define C2_ (0.125f * 1.44269504088896f)   // scale * log2(e)

typedef __attribute__((ext_vector_type(8))) _Float16 f16x8;
typedef __attribute__((ext_vector_type(4))) float f32x4;
typedef unsigned short u16;
typedef unsigned int   u32;

__device__ inline u16 f2h(float f) {             // RNE fp32->fp16 (HW cvt)
    union { _Float16 h; u16 u; } c; c.h = (_Float16)f;
    return c.u;
}
__device__ inline float h2f(u16 h) {
    union { u16 u; _Float16 h; } c; c.u = h;
    return (float)c.h;
}
__device__ inline u32 pack_h2(float a, float b) {  // [lo16=h(a), hi16=h(b)]
    return (u32)f2h(a) | ((u32)f2h(b) << 16);
}

// ---------------------------------------------------------------------------
// Pre-cast all six tensors to fp16. z: 0=wq 1=wk 2=wv 3=q 4=k 5=v
// ---------------------------------------------------------------------------
__global__ __launch_bounds__(256)
void precast(const float* __restrict__ wq, const float* __restrict__ wk,
             const float* __restrict__ wv, const float* __restrict__ q,
             const float* __restrict__ k,  const float* __restrict__ v,
             u16* __restrict__ Wq, u16* __restrict__ Wk, u16* __restrict__ Wv,
             u16* __restrict__ Xq, u16* __restrict__ Xk, u16* __restrict__ Xv)
{
    const int z = blockIdx.y;
    const size_t n = (z >= 3) ? (size_t)B_ * S_ * D_ : (size_t)D_ * D_;
    const size_t i = ((size_t)blockIdx.x * 256 + threadIdx.x) * 4;
    if (i >= n) return;
    const float* src = (z == 0) ? wq : (z == 1) ? wk : (z == 2) ? wv
                     : (z == 3) ? q  : (z == 4) ? k  : v;
    u16* dst = (z == 0) ? Wq : (z == 1) ? Wk : (z == 2) ? Wv
             : (z == 3) ? Xq : (z == 4) ? Xk : Xv;
    float4 xv = *(const float4*)&src[i];
    *(ushort4*)&dst[i] = make_ushort4(f2h(xv.x), f2h(xv.y), f2h(xv.z), f2h(xv.w));
}

// ---------------------------------------------------------------------------
// Unified projection GEMM, fp16 single-product. 128x128 tile, 4 waves,
// BK=64, 2x8 register-blocked 16x16x32 frags. z picks (X,W,out).
// z<2: out [b,h,s,hd]; z==2: out TRANSPOSED [b,h,vd,s] (ushort4 stores).
// ---------------------------------------------------------------------------
__global__ __launch_bounds__(256)
void proj_all(const u16* __restrict__ Xq, const u16* __restrict__ Xk,
              const u16* __restrict__ Xv, const u16* __restrict__ Wq,
              const u16* __restrict__ Wk, const u16* __restrict__ Wv,
              u16* __restrict__ QP, u16* __restrict__ KP, u16* __restrict__ VT)
{
    const int z = blockIdx.z;
    const u16* X = (z == 0) ? Xq : (z == 1) ? Xk : Xv;
    const u16* W = (z == 0) ? Wq : (z == 1) ? Wk : Wv;

    __shared__ u16 Xs[128][72];   // [m][k], rows 144 B (16B-aligned)
    __shared__ u16 Ws[128][72];   // [n][k]

    const int tid  = threadIdx.x;
    const int w    = tid >> 6;
    const int lane = tid & 63;
    const int quad = lane >> 4;
    const int lr   = lane & 15;
    const int rr   = tid >> 1;          // loader row 0..127
    const int kb   = (tid & 1) * 32;    // loader k half
    const int m0   = blockIdx.y * 128;
    const int n0   = blockIdx.x * 128;

    f32x4 acc[2][8];
    #pragma unroll
    for (int i = 0; i < 2; ++i)
        #pragma unroll
        for (int j = 0; j < 8; ++j) acc[i][j] = (f32x4){0.f, 0.f, 0.f, 0.f};

    for (int k0 = 0; k0 < D_; k0 += 64) {
        f16x8 xv[4], wv[4];
        #pragma unroll
        for (int c = 0; c < 4; ++c) {
            xv[c] = *(const f16x8*)&X[(size_t)(m0 + rr) * D_ + k0 + kb + c * 8];
            wv[c] = *(const f16x8*)&W[(size_t)(n0 + rr) * D_ + k0 + kb + c * 8];
        }
        __syncthreads();
        #pragma unroll
        for (int c = 0; c < 4; ++c) {
            *(f16x8*)&Xs[rr][kb + c * 8] = xv[c];
            *(f16x8*)&Ws[rr][kb + c * 8] = wv[c];
        }
        __syncthreads();

        #pragma unroll
        for (int ch = 0; ch < 2; ++ch) {
            f16x8 a[2];
            #pragma unroll
            for (int i = 0; i < 2; ++i)
                a[i] = *(const f16x8*)&Xs[w * 32 + i * 16 + lr][ch * 32 + quad * 8];
            #pragma unroll
            for (int j = 0; j < 8; ++j) {
                f16x8 b = *(const f16x8*)&Ws[j * 16 + lr][ch * 32 + quad * 8];
                #pragma unroll
                for (int i = 0; i < 2; ++i)
                    acc[i][j] = __builtin_amdgcn_mfma_f32_16x16x32_f16(a[i], b, acc[i][j], 0, 0, 0);
            }
        }
    }

    if (z < 2) {
        u16* P = (z == 0) ? QP : KP;
        #pragma unroll
        for (int i = 0; i < 2; ++i)
            #pragma unroll
            for (int j = 0; j < 8; ++j) {
                int n = n0 + j * 16 + lr;
                int h = n >> 6, hd = n & 63;
                #pragma unroll
                for (int r = 0; r < 4; ++r) {
                    int m = m0 + w * 32 + i * 16 + quad * 4 + r;
                    int b = m >> 11, s = m & (S_ - 1);
                    P[(((size_t)b * H_ + h) * S_ + s) * HD_ + hd] = f2h(acc[i][j][r]);
                }
            }
    } else {
        #pragma unroll
        for (int i = 0; i < 2; ++i)
            #pragma unroll
            for (int j = 0; j < 8; ++j) {
                int n  = n0 + j * 16 + lr;
                int h  = n >> 6, vd = n & 63;
                int m  = m0 + w * 32 + i * 16 + quad * 4;   // 4 consecutive s
                int b  = m >> 11, s = m & (S_ - 1);
                ushort4 pv = make_ushort4(f2h(acc[i][j][0]), f2h(acc[i][j][1]),
                                          f2h(acc[i][j][2]), f2h(acc[i][j][3]));
                *(ushort4*)&VT[(((size_t)b * H_ + h) * HD_ + vd) * S_ + s] = pv;
            }
    }
}

// ---------------------------------------------------------------------------
// V tile sums (fp16 VT) + suffix sums
// ---------------------------------------------------------------------------
__global__ __launch_bounds__(64)
void vtilesum_kernel(const u16* __restrict__ VT, float* __restrict__ TS)
{
    const int t = blockIdx.x, bh = blockIdx.y, vd = threadIdx.x;
    const size_t base = ((size_t)bh * HD_ + vd) * S_ + t * 64;
    float acc = 0.f;
    #pragma unroll
    for (int j = 0; j < 64; ++j) acc += h2f(VT[base + j]);
    TS[((size_t)bh * NT_ + t) * HD_ + vd] = acc;
}

__global__ __launch_bounds__(64)
void vsuffix_kernel(const float* __restrict__ TS, float* __restrict__ SUF)
{
    const int bh = blockIdx.x, c = threadIdx.x;
    float acc = 0.f;
    SUF[((size_t)bh * (NT_ + 1) + NT_) * HD_ + c] = 0.f;
    for (int t = NT_ - 1; t >= 0; --t) {
        acc += TS[((size_t)bh * NT_ + t) * HD_ + c];
        SUF[((size_t)bh * (NT_ + 1) + t) * HD_ + c] = acc;
    }
}

// ---------------------------------------------------------------------------
// Transposed-score fp16 MFMA flash attention.
// S^T = K·Q^T (C: col=q=lane&15, row=key=quad*4+reg): each lane owns one
// q-row -> softmax = in-lane + 2 shfl_xor. P fp16 -> LDS round-trip ->
// O^T += V^T·P^T. K/VT tiles LDS-staged, reg-prefetched. Paired q-tiles
// (tq, NT-1-tq): 512 uniform blocks x 33 tile-iters (no triangular tail).
// Zeroed-upper-triangle softmax via analytic V-suffix tail. LDS 27.6 KB.
// ---------------------------------------------------------------------------
__global__ __launch_bounds__(256)
void attn_mfma(const u16* __restrict__ QP, const u16* __restrict__ KP,
               const u16* __restrict__ VT, const float* __restrict__ SUF,
               float* __restrict__ OUT)
{
    const int pr = blockIdx.x;           // 0..15
    const int bh = blockIdx.y;
    const int b  = bh >> 4, h = bh & 15;

    __shared__ u16 Ks[64][72];       // [key][d]   fp16
    __shared__ u16 Vth[64][72];      // [vd][key]  fp16
    __shared__ u16 Phi[4][16][72];   // [wave][q][key] fp16

    const int tid  = threadIdx.x;
    const int w    = tid >> 6;
    const int lane = tid & 63;
    const int quad = lane >> 4;
    const int lr   = lane & 15;
    const int r    = tid >> 2;          // stage row 0..63
    const int cb   = (tid & 3) * 16;    // stage col base (cb..cb+15)

    const u16* Qb = QP + (size_t)bh * S_ * HD_;
    const u16* Kb = KP + (size_t)bh * S_ * HD_;
    const u16* Vb = VT + (size_t)bh * HD_ * S_;

    #pragma unroll
    for (int sub = 0; sub < 2; ++sub) {
        const int tq = sub ? pr : (NT_ - 1 - pr);
        const int q0 = tq * 64;

        f16x8 qf[2];
        #pragma unroll
        for (int ch = 0; ch < 2; ++ch)
            qf[ch] = *(const f16x8*)(Qb + (size_t)(q0 + w * 16 + lr) * HD_ +
                                     ch * 32 + quad * 8);

        f32x4 of[4];
        #pragma unroll
        for (int n = 0; n < 4; ++n) of[n] = (f32x4){0.f, 0.f, 0.f, 0.f};
        float m_i = -1e30f, l_i = 0.f;

        f16x8 kpre[2], vpre[2];
        #pragma unroll
        for (int c = 0; c < 2; ++c) {
            kpre[c] = *(const f16x8*)(Kb + (size_t)r * HD_ + cb + c * 8);
            vpre[c] = *(const f16x8*)(Vb + (size_t)r * S_ + cb + c * 8);
        }

        for (int t = 0; t <= tq; ++t) {
            const int k0t = t * 64;
            __syncthreads();   // (A) prior iteration's tile reads done
            #pragma unroll
            for (int c = 0; c < 2; ++c) {
                *(f16x8*)&Ks[r][cb + c * 8]  = kpre[c];
                *(f16x8*)&Vth[r][cb + c * 8] = vpre[c];
            }
            __syncthreads();   // (B) tiles visible
            if (t < tq) {
                const int kn = k0t + 64;
                #pragma unroll
                for (int c = 0; c < 2; ++c) {
                    kpre[c] = *(const f16x8*)(Kb + (size_t)(kn + r) * HD_ + cb + c * 8);
                    vpre[c] = *(const f16x8*)(Vb + (size_t)r * S_ + kn + cb + c * 8);
                }
            }

            // ---- S^T = K Q^T ----
            f32x4 sf[4];
            #pragma unroll
            for (int f = 0; f < 4; ++f) sf[f] = (f32x4){0.f, 0.f, 0.f, 0.f};
            #pragma unroll
            for (int ch = 0; ch < 2; ++ch)
                #pragma unroll
                for (int f = 0; f < 4; ++f) {
                    f16x8 ak = *(const f16x8*)&Ks[f * 16 + lr][ch * 32 + quad * 8];
                    sf[f] = __builtin_amdgcn_mfma_f32_16x16x32_f16(ak, qf[ch], sf[f], 0, 0, 0);
                }

            // ---- scale (log2 domain) + zero-mask (diagonal tile only) ----
            const int ig = q0 + w * 16 + lr;
            if (t == tq) {
                #pragma unroll
                for (int f = 0; f < 4; ++f)
                    #pragma unroll
                    for (int i = 0; i < 4; ++i) {
                        int jg = k0t + f * 16 + quad * 4 + i;
                        sf[f][i] = (jg <= ig) ? sf[f][i] * C2_ : 0.f;
                    }
            } else {
                #pragma unroll
                for (int f = 0; f < 4; ++f) sf[f] *= C2_;
            }

            // ---- online softmax (base 2): in-lane + 2 shfls ----
            float mx = fmaxf(fmaxf(fmaxf(sf[0][0], sf[0][1]), fmaxf(sf[0][2], sf[0][3])),
                             fmaxf(fmaxf(sf[1][0], sf[1][1]), fmaxf(sf[1][2], sf[1][3])));
            mx = fmaxf(mx,
                 fmaxf(fmaxf(fmaxf(sf[2][0], sf[2][1]), fmaxf(sf[2][2], sf[2][3])),
                       fmaxf(fmaxf(sf[3][0], sf[3][1]), fmaxf(sf[3][2], sf[3][3]))));
            mx = fmaxf(mx, __shfl_xor(mx, 16));
            mx = fmaxf(mx, __shfl_xor(mx, 32));
            float mn    = fmaxf(m_i, mx);
            float alpha = exp2f(m_i - mn);
            m_i = mn;
            float ps = 0.f;
            #pragma unroll
            for (int f = 0; f < 4; ++f)
                #pragma unroll
                for (int i = 0; i < 4; ++i) {
                    float p = exp2f(sf[f][i] - mn);
                    sf[f][i] = p;
                    ps += p;
                }
            ps += __shfl_xor(ps, 16);
            ps += __shfl_xor(ps, 32);
            l_i = l_i * alpha + ps;
            #pragma unroll
            for (int n = 0; n < 4; ++n) of[n] *= alpha;

            // ---- P -> LDS as fp16 ----
            #pragma unroll
            for (int f = 0; f < 4; ++f) {
                *(u32*)&Phi[w][lr][f * 16 + quad * 4]     = pack_h2(sf[f][0], sf[f][1]);
                *(u32*)&Phi[w][lr][f * 16 + quad * 4 + 2] = pack_h2(sf[f][2], sf[f][3]);
            }

            // ---- O^T += V^T P^T  (in-wave LDS ordering; no barrier) ----
            #pragma unroll
            for (int ch = 0; ch < 2; ++ch) {
                f16x8 pb = *(const f16x8*)&Phi[w][lr][ch * 32 + quad * 8];
                #pragma unroll
                for (int n = 0; n < 4; ++n) {
                    f16x8 av = *(const f16x8*)&Vth[n * 16 + lr][ch * 32 + quad * 8];
                    of[n] = __builtin_amdgcn_mfma_f32_16x16x32_f16(av, pb, of[n], 0, 0, 0);
                }
            }
        }

        // ---- masked-suffix contribution + normalize + store (float4) ----
        const int cnt = S_ - (q0 + 64);
        const float* suf = SUF + ((size_t)bh * (NT_ + 1) + (tq + 1)) * HD_;
        float we    = exp2f(-m_i);
        float denom = l_i + we * (float)cnt;
        float inv   = 1.0f / denom;
        const int srow = q0 + w * 16 + lr;
        #pragma unroll
        for (int n = 0; n < 4; ++n) {
            float4 sv = *(const float4*)&suf[n * 16 + quad * 4];
            float4 ov;
            ov.x = (of[n][0] + we * sv.x) * inv;
            ov.y = (of[n][1] + we * sv.y) * inv;
            ov.z = (of[n][2] + we * sv.z) * inv;
            ov.w = (of[n][3] + we * sv.w) * inv;
            *(float4*)&OUT[((size_t)b * S_ + srow) * D_ + h * HD_ + n * 16 + quad * 4] = ov;
        }
    }
}

// ---------------------------------------------------------------------------
extern "C" void kernel_launch(void* const* d_in, const int* in_sizes, int n_in,
                              void* d_out, int out_size, void* d_ws, size_t ws_size,
                              hipStream_t stream)
{
    (void)in_sizes; (void)n_in; (void)out_size; (void)ws_size;
    const float* q  = (const float*)d_in[0];
    const float* k  = (const float*)d_in[1];
    const float* v  = (const float*)d_in[2];
    const float* wq = (const float*)d_in[3];
    const float* wk = (const float*)d_in[4];
    const float* wv = (const float*)d_in[5];
    float* out = (float*)d_out;

    const size_t PROJ = (size_t)B_ * H_ * S_ * HD_;     // 4,194,304 elems
    const size_t WSZ  = (size_t)D_ * D_;                // 1,048,576 elems
    u16* QP = (u16*)d_ws;
    u16* KP = QP + PROJ;
    u16* VT = KP + PROJ;
    u16* Xq = VT + PROJ;
    u16* Xk = Xq + PROJ;
    u16* Xv = Xk + PROJ;
    u16* Wq = Xv + PROJ;
    u16* Wk = Wq + WSZ;
    u16* Wv = Wk + WSZ;
    float* TS  = (float*)(Wv + WSZ);
    float* SUF = TS + (size_t)B_ * H_ * NT_ * HD_;

    precast<<<dim3(PROJ / 1024, 6), 256, 0, stream>>>(
        wq, wk, wv, q, k, v, Wq, Wk, Wv, Xq, Xk, Xv);
    proj_all<<<dim3(D_ / 128, (B_ * S_) / 128, 3), 256, 0, stream>>>(
        Xq, Xk, Xv, Wq, Wk, Wv, QP, KP, VT);
    vtilesum_kernel<<<dim3(NT_, B_ * H_), 64, 0, stream>>>(VT, TS);
    vsuffix_kernel<<<B_ * H_, 64, 0, stream>>>(TS, SUF);
    attn_mfma<<<dim3(NT_ / 2, B_ * H_), 256, 0, stream>>>(QP, KP, VT, SUF, out);
}